// Round 2
// baseline (385.604 us; speedup 1.0000x reference)
//
#include <hip/hip_runtime.h>

// ---------- helpers ----------
typedef __attribute__((ext_vector_type(8))) __bf16 bf16x8;
typedef __attribute__((ext_vector_type(4))) float f32x4;

__device__ inline unsigned short f2bf(float f) {
    union { float f; unsigned int i; } v; v.f = f;
    unsigned int i = v.i;
    unsigned int r = i + 0x7FFFu + ((i >> 16) & 1u);   // RNE
    return (unsigned short)(r >> 16);
}
__device__ inline float bf2f(unsigned short u) {
    union { unsigned int i; float f; } v; v.i = ((unsigned int)u) << 16; return v.f;
}

__device__ inline void gload_lds16(const void* g, void* l) {
    __builtin_amdgcn_global_load_lds(
        (const __attribute__((address_space(1))) unsigned int*)g,
        (__attribute__((address_space(3))) unsigned int*)l, 16, 0, 0);
}

// ---------- kernel 1: cast x (fp32 -> bf16) ----------
__global__ __launch_bounds__(256) void cast_x(const float* __restrict__ x,
                                              unsigned short* __restrict__ xb, int n4) {
    int idx = blockIdx.x * blockDim.x + threadIdx.x;
    int stride = gridDim.x * blockDim.x;
    for (int i = idx; i < n4; i += stride) {
        float4 v = ((const float4*)x)[i];
        ushort4 o;
        o.x = f2bf(v.x); o.y = f2bf(v.y); o.z = f2bf(v.z); o.w = f2bf(v.w);
        ((ushort4*)xb)[i] = o;
    }
}

// ---------- kernel 2: cast W into Wcat rows 0..1023 ----------
__global__ __launch_bounds__(256) void cast_w(const float* __restrict__ W,
                                              unsigned short* __restrict__ wcat) {
    int i = blockIdx.x * 256 + threadIdx.x;
    float4 v = ((const float4*)W)[i];
    ushort4 o;
    o.x = f2bf(v.x); o.y = f2bf(v.y); o.z = f2bf(v.z); o.w = f2bf(v.w);
    ((ushort4*)wcat)[i] = o;
}

// ---------- kernel 3: build M^T into Wcat rows 1024..2047 ----------
__global__ __launch_bounds__(256) void build_m(const float* __restrict__ A,
                                               const float* __restrict__ Bm,
                                               const float* __restrict__ scores,
                                               unsigned short* __restrict__ wcat) {
    int D = blockIdx.x;      // 1024
    int tx = threadIdx.x;    // 256
    float acc[4] = {0.f, 0.f, 0.f, 0.f};
    for (int e = 0; e < 16; ++e) {
        float pe = scores[e];
        float bb[16];
        #pragma unroll
        for (int r = 0; r < 16; ++r) bb[r] = pe * Bm[(size_t)((e << 4) + r) * 1024 + D];
        #pragma unroll
        for (int j = 0; j < 4; ++j) {
            int d = tx + j * 256;
            const float4* ap = (const float4*)(A + (((size_t)e * 1024 + d) << 4));
            float4 a0 = ap[0], a1 = ap[1], a2 = ap[2], a3 = ap[3];
            acc[j] += a0.x*bb[0]  + a0.y*bb[1]  + a0.z*bb[2]  + a0.w*bb[3]
                    + a1.x*bb[4]  + a1.y*bb[5]  + a1.z*bb[6]  + a1.w*bb[7]
                    + a2.x*bb[8]  + a2.y*bb[9]  + a2.z*bb[10] + a2.w*bb[11]
                    + a3.x*bb[12] + a3.y*bb[13] + a3.z*bb[14] + a3.w*bb[15];
        }
    }
    size_t rowbase = (size_t)(1024 + D) * 1024;
    #pragma unroll
    for (int j = 0; j < 4; ++j) wcat[rowbase + tx + j * 256] = f2bf(acc[j]);
}

// ---------- kernel 4: 256x256-tile 8-phase GEMM ----------
// out2[t][n] = sum_k xb[t][k] * wcat[n][k];  M=32768, N=2048, K=1024.
// BM=BN=256, BK=64, 8 waves (2Mx4N), 128KiB dynamic LDS, double-buffered.
// LDS layout per K-tile buffer (64KB): A_k0 | A_k1 | B_k0 | B_k1, each 16KB
// stored chunk-major [4 chunks of 8 bf16][256 rows][16B] -> conflict-free
// ds_read_b128 frag reads (banks 4r mod 32, 2-way = free) AND linear
// global_load_lds staging (per-lane global src handles the transposition).
__global__ __launch_bounds__(512, 2) void gemm_zm8(const unsigned short* __restrict__ xb,
                                                   const unsigned short* __restrict__ wcat,
                                                   const float* __restrict__ bias,
                                                   float* __restrict__ zout,
                                                   unsigned short* __restrict__ mbuf) {
    extern __shared__ char lds[];
    const int tid = threadIdx.x;
    const int l = tid & 63;
    const int w = tid >> 6;
    const int wr = w >> 2;        // 0..1  (M half)
    const int wc = w & 3;         // 0..3  (N quarter)

    // XCD-aware swizzle: 1024 blocks, 8 XCDs, contiguous tile_m runs per XCD
    const int bid = blockIdx.x;
    const int swz = (bid & 7) * 128 + (bid >> 3);
    const int brow = (swz >> 3) * 256;    // 128 M-tiles
    const int bcol = (swz & 7) * 256;     // 8 N-tiles

    const int lco = (l >> 4) * 4096 + (l & 15) * 16;  // chunk-major frag offset
    const int sr = tid & 255;     // staging row
    const int sc = tid >> 8;      // staging chunk base (0/1)

    f32x4 acc[8][4] = {};

#define STAGE(mat, baserow, T, h, breg) do {                                        \
        int T_ = (T);                                                               \
        int Ts_ = T_ > 15 ? 15 : T_;                                                \
        char* rg_ = lds + ((T_ & 1) * 65536 + (breg) + (h) * 16384);                \
        const unsigned short* g_ = (mat) + (size_t)((baserow) + sr) * 1024          \
                                   + Ts_ * 64 + (h) * 32 + sc * 8;                  \
        gload_lds16(g_,      rg_ + sc * 4096 + sr * 16);                            \
        gload_lds16(g_ + 16, rg_ + (sc + 2) * 4096 + sr * 16);                      \
    } while (0)

#define RDA(buf, ks, mf) (*(const bf16x8*)(lds + (buf) * 65536 + (ks) * 16384 + lco + wr * 2048 + (mf) * 256))
#define RDB(buf, ks, nf) (*(const bf16x8*)(lds + (buf) * 65536 + 32768 + (ks) * 16384 + lco + wc * 1024 + (nf) * 256))

#define PHASE_SYNC() do {                                                           \
        __builtin_amdgcn_s_barrier();                                               \
        asm volatile("s_waitcnt lgkmcnt(0)" ::: "memory");                          \
        __builtin_amdgcn_sched_barrier(0);                                          \
    } while (0)

    // ---- prologue: tile0 fully + tile1 k0 halves (6 half-tiles, 12 loads) ----
    STAGE(xb,   brow, 0, 0, 0);
    STAGE(wcat, bcol, 0, 0, 32768);
    STAGE(xb,   brow, 0, 1, 0);
    STAGE(wcat, bcol, 0, 1, 32768);
    STAGE(xb,   brow, 1, 0, 0);
    STAGE(wcat, bcol, 1, 0, 32768);
    asm volatile("s_waitcnt vmcnt(4)" ::: "memory");   // tile0 landed; tile1-k0 in flight
    __builtin_amdgcn_s_barrier();

    for (int t = 0; t < 16; ++t) {
        const int buf = t & 1;
        bf16x8 a[4], a2[4], b[4];

        // ---- phase 0: k0, m-frags 0-3 ----
        #pragma unroll
        for (int mf = 0; mf < 4; ++mf) a[mf] = RDA(buf, 0, mf);
        #pragma unroll
        for (int nf = 0; nf < 4; ++nf) b[nf] = RDB(buf, 0, nf);
        STAGE(xb, brow, t + 1, 1, 0);               // A-k1(t+1) -> other buf
        PHASE_SYNC();
        __builtin_amdgcn_s_setprio(1);
        #pragma unroll
        for (int mf = 0; mf < 4; ++mf)
            #pragma unroll
            for (int nf = 0; nf < 4; ++nf)
                acc[mf][nf] = __builtin_amdgcn_mfma_f32_16x16x32_bf16(a[mf], b[nf], acc[mf][nf], 0, 0, 0);
        __builtin_amdgcn_s_setprio(0);
        __builtin_amdgcn_s_barrier();

        // ---- phase 1: k0, m-frags 4-7 (reuse b) ----
        #pragma unroll
        for (int mf = 0; mf < 4; ++mf) a2[mf] = RDA(buf, 0, mf + 4);
        STAGE(wcat, bcol, t + 1, 1, 32768);         // B-k1(t+1) -> other buf
        PHASE_SYNC();
        __builtin_amdgcn_s_setprio(1);
        #pragma unroll
        for (int mf = 0; mf < 4; ++mf)
            #pragma unroll
            for (int nf = 0; nf < 4; ++nf)
                acc[mf + 4][nf] = __builtin_amdgcn_mfma_f32_16x16x32_bf16(a2[mf], b[nf], acc[mf + 4][nf], 0, 0, 0);
        __builtin_amdgcn_s_setprio(0);
        __builtin_amdgcn_s_barrier();

        // ---- phase 2: k1, m-frags 0-3 ----
        #pragma unroll
        for (int mf = 0; mf < 4; ++mf) a[mf] = RDA(buf, 1, mf);
        #pragma unroll
        for (int nf = 0; nf < 4; ++nf) b[nf] = RDB(buf, 1, nf);
        STAGE(xb, brow, t + 2, 0, 0);               // A-k0(t+2) -> this buf (reads done ph1)
        PHASE_SYNC();
        __builtin_amdgcn_s_setprio(1);
        #pragma unroll
        for (int mf = 0; mf < 4; ++mf)
            #pragma unroll
            for (int nf = 0; nf < 4; ++nf)
                acc[mf][nf] = __builtin_amdgcn_mfma_f32_16x16x32_bf16(a[mf], b[nf], acc[mf][nf], 0, 0, 0);
        __builtin_amdgcn_s_setprio(0);
        __builtin_amdgcn_s_barrier();

        // ---- phase 3: k1, m-frags 4-7 ----
        #pragma unroll
        for (int mf = 0; mf < 4; ++mf) a2[mf] = RDA(buf, 1, mf + 4);
        STAGE(wcat, bcol, t + 2, 0, 32768);         // B-k0(t+2) -> this buf (reads done ph0)
        PHASE_SYNC();
        __builtin_amdgcn_s_setprio(1);
        #pragma unroll
        for (int mf = 0; mf < 4; ++mf)
            #pragma unroll
            for (int nf = 0; nf < 4; ++nf)
                acc[mf + 4][nf] = __builtin_amdgcn_mfma_f32_16x16x32_bf16(a2[mf], b[nf], acc[mf + 4][nf], 0, 0, 0);
        __builtin_amdgcn_s_setprio(0);
        // counted vmcnt: leave newest 2 half-tiles (phase-2/3 stages) in flight
        asm volatile("s_waitcnt vmcnt(4)" ::: "memory");
        __builtin_amdgcn_s_barrier();
    }

    // ---- C-write epilogue ----
    const bool is_z = (bcol < 1024);
    const int crow0 = brow + wr * 128 + (l >> 4) * 4;
    const int ccol0 = bcol + wc * 64 + (l & 15);
    #pragma unroll
    for (int nf = 0; nf < 4; ++nf) {
        int col = ccol0 + nf * 16;
        if (is_z) {
            float bb = bias[col];
            #pragma unroll
            for (int mf = 0; mf < 8; ++mf) {
                int row = crow0 + mf * 16;
                f32x4 v = acc[mf][nf];
                #pragma unroll
                for (int j = 0; j < 4; ++j)
                    zout[(size_t)(row + j) * 1024 + col] = v[j] + bb;
            }
        } else {
            int mc = col - 1024;
            #pragma unroll
            for (int mf = 0; mf < 8; ++mf) {
                int row = crow0 + mf * 16;
                f32x4 v = acc[mf][nf];
                #pragma unroll
                for (int j = 0; j < 4; ++j)
                    mbuf[(size_t)(row + j) * 1024 + mc] = f2bf(v[j]);
            }
        }
    }
#undef STAGE
#undef RDA
#undef RDB
#undef PHASE_SYNC
}

// ---------- kernel 5: norm-clamp epilogue, rewrites d_out in place ----------
__global__ __launch_bounds__(256) void epilogue(float* __restrict__ out,
                                                const unsigned short* __restrict__ mbuf,
                                                const int* __restrict__ lidx) {
    int row = blockIdx.x;            // 32768
    int tx = threadIdx.x;            // 256
    size_t base = (size_t)row * 1024 + tx * 4;

    float4 z = *(const float4*)&out[base];
    ushort4 mv = *(const ushort4*)&mbuf[base];
    float m0 = bf2f(mv.x), m1 = bf2f(mv.y), m2 = bf2f(mv.z), m3 = bf2f(mv.w);

    float sz = z.x * z.x + z.y * z.y + z.z * z.z + z.w * z.w;
    float sm = m0 * m0 + m1 * m1 + m2 * m2 + m3 * m3;

    #pragma unroll
    for (int off = 32; off > 0; off >>= 1) {
        sz += __shfl_xor(sz, off);
        sm += __shfl_xor(sm, off);
    }
    __shared__ float red[8];
    int wv = tx >> 6;
    if ((tx & 63) == 0) { red[wv * 2] = sz; red[wv * 2 + 1] = sm; }
    __syncthreads();
    sz = red[0] + red[2] + red[4] + red[6];
    sm = red[1] + red[3] + red[5] + red[7];

    float gamma = fminf(0.5f * sqrtf(sz) / (sqrtf(sm) + 1e-6f), 1.0f);
    if (lidx[0] < 0) gamma = 0.f;

    float4 o;
    o.x = z.x + gamma * m0; o.y = z.y + gamma * m1;
    o.z = z.z + gamma * m2; o.w = z.w + gamma * m3;
    *(float4*)&out[base] = o;
}

// ---------- launcher ----------
extern "C" void kernel_launch(void* const* d_in, const int* in_sizes, int n_in,
                              void* d_out, int out_size, void* d_ws, size_t ws_size,
                              hipStream_t stream) {
    const float* x  = (const float*)d_in[0];
    const float* W  = (const float*)d_in[1];
    const float* b  = (const float*)d_in[2];
    const float* A  = (const float*)d_in[3];
    const float* Bm = (const float*)d_in[4];
    const float* sc = (const float*)d_in[5];
    const int* lidx = (const int*)d_in[6];
    float* out = (float*)d_out;

    // workspace layout (bytes): xb 64MB | wcat 4MB | mbuf 64MB
    unsigned short* xb   = (unsigned short*)d_ws;
    unsigned short* wcat = (unsigned short*)((char*)d_ws + 67108864);
    unsigned short* mbuf = (unsigned short*)((char*)d_ws + 71303168);

    static bool attr_set = false;   // idempotent host-side attribute (not a stream op)
    if (!attr_set) {
        hipFuncSetAttribute((const void*)gemm_zm8,
                            hipFuncAttributeMaxDynamicSharedMemorySize, 131072);
        attr_set = true;
    }

    cast_x<<<2048, 256, 0, stream>>>(x, xb, 33554432 / 4);
    cast_w<<<1024, 256, 0, stream>>>(W, wcat);
    build_m<<<1024, 256, 0, stream>>>(A, Bm, sc, wcat);
    gemm_zm8<<<1024, 512, 131072, stream>>>(xb, wcat, b, out, mbuf);
    epilogue<<<32768, 256, 0, stream>>>(out, mbuf, lidx);
}

// Round 3
// 377.260 us; speedup vs baseline: 1.0221x; 1.0221x over previous
//
#include <hip/hip_runtime.h>

// ---------- helpers ----------
typedef __attribute__((ext_vector_type(8))) __bf16 bf16x8;
typedef __attribute__((ext_vector_type(4))) float f32x4;

__device__ inline unsigned short f2bf(float f) {
    union { float f; unsigned int i; } v; v.f = f;
    unsigned int i = v.i;
    unsigned int r = i + 0x7FFFu + ((i >> 16) & 1u);   // RNE
    return (unsigned short)(r >> 16);
}
__device__ inline float bf2f(unsigned short u) {
    union { unsigned int i; float f; } v; v.i = ((unsigned int)u) << 16; return v.f;
}

__device__ inline void gload_lds16(const void* g, void* l) {
    __builtin_amdgcn_global_load_lds(
        (const __attribute__((address_space(1))) unsigned int*)g,
        (__attribute__((address_space(3))) unsigned int*)l, 16, 0, 0);
}

// ---------- kernel 1: cast x (fp32 -> bf16) ----------
__global__ __launch_bounds__(256) void cast_x(const float* __restrict__ x,
                                              unsigned short* __restrict__ xb, int n4) {
    int idx = blockIdx.x * blockDim.x + threadIdx.x;
    int stride = gridDim.x * blockDim.x;
    for (int i = idx; i < n4; i += stride) {
        float4 v = ((const float4*)x)[i];
        ushort4 o;
        o.x = f2bf(v.x); o.y = f2bf(v.y); o.z = f2bf(v.z); o.w = f2bf(v.w);
        ((ushort4*)xb)[i] = o;
    }
}

// ---------- kernel 2: cast W into Wcat rows 0..1023 ----------
__global__ __launch_bounds__(256) void cast_w(const float* __restrict__ W,
                                              unsigned short* __restrict__ wcat) {
    int i = blockIdx.x * 256 + threadIdx.x;
    float4 v = ((const float4*)W)[i];
    ushort4 o;
    o.x = f2bf(v.x); o.y = f2bf(v.y); o.z = f2bf(v.z); o.w = f2bf(v.w);
    ((ushort4*)wcat)[i] = o;
}

// ---------- kernel 3: build M^T into Wcat rows 1024..2047 ----------
__global__ __launch_bounds__(256) void build_m(const float* __restrict__ A,
                                               const float* __restrict__ Bm,
                                               const float* __restrict__ scores,
                                               unsigned short* __restrict__ wcat) {
    int D = blockIdx.x;      // 1024
    int tx = threadIdx.x;    // 256
    float acc[4] = {0.f, 0.f, 0.f, 0.f};
    for (int e = 0; e < 16; ++e) {
        float pe = scores[e];
        float bb[16];
        #pragma unroll
        for (int r = 0; r < 16; ++r) bb[r] = pe * Bm[(size_t)((e << 4) + r) * 1024 + D];
        #pragma unroll
        for (int j = 0; j < 4; ++j) {
            int d = tx + j * 256;
            const float4* ap = (const float4*)(A + (((size_t)e * 1024 + d) << 4));
            float4 a0 = ap[0], a1 = ap[1], a2 = ap[2], a3 = ap[3];
            acc[j] += a0.x*bb[0]  + a0.y*bb[1]  + a0.z*bb[2]  + a0.w*bb[3]
                    + a1.x*bb[4]  + a1.y*bb[5]  + a1.z*bb[6]  + a1.w*bb[7]
                    + a2.x*bb[8]  + a2.y*bb[9]  + a2.z*bb[10] + a2.w*bb[11]
                    + a3.x*bb[12] + a3.y*bb[13] + a3.z*bb[14] + a3.w*bb[15];
        }
    }
    size_t rowbase = (size_t)(1024 + D) * 1024;
    #pragma unroll
    for (int j = 0; j < 4; ++j) wcat[rowbase + tx + j * 256] = f2bf(acc[j]);
}

// ---------- kernel 4: 256x256-tile 8-phase GEMM ----------
// out2[t][n] = sum_k xb[t][k] * wcat[n][k];  M=32768, N=2048, K=1024.
// BM=BN=256, BK=64, 8 waves (2Mx4N), 128KiB dynamic LDS, double-buffered.
// Chunk-major LDS [4 chunks][256 rows][16B]: conflict-free ds_read_b128 AND
// linear global_load_lds staging. NO per-phase sched walls (m141 lesson):
// compiler manages lgkmcnt; raw barriers + setprio; one counted vmcnt/K-tile.
__global__ __launch_bounds__(512, 2) void gemm_zm8(const unsigned short* __restrict__ xb,
                                                   const unsigned short* __restrict__ wcat,
                                                   const float* __restrict__ bias,
                                                   float* __restrict__ zout,
                                                   unsigned short* __restrict__ mbuf,
                                                   unsigned short* __restrict__ obuf,
                                                   int unified) {
    extern __shared__ char lds[];
    const int tid = threadIdx.x;
    const int l = tid & 63;
    const int w = tid >> 6;
    const int wr = w >> 2;        // 0..1  (M half)
    const int wc = w & 3;         // 0..3  (N quarter)

    const int bid = blockIdx.x;
    const int swz = (bid & 7) * 128 + (bid >> 3);
    const int brow = (swz >> 3) * 256;    // 128 M-tiles
    const int bcol = (swz & 7) * 256;     // 8 N-tiles

    const int lco = (l >> 4) * 4096 + (l & 15) * 16;
    const int sr = tid & 255;
    const int sc = tid >> 8;

    f32x4 acc[8][4] = {};

#define STAGE(mat, baserow, T, h, breg) do {                                        \
        int T_ = (T);                                                               \
        int Ts_ = T_ > 15 ? 15 : T_;                                                \
        char* rg_ = lds + ((T_ & 1) * 65536 + (breg) + (h) * 16384);                \
        const unsigned short* g_ = (mat) + (size_t)((baserow) + sr) * 1024          \
                                   + Ts_ * 64 + (h) * 32 + sc * 8;                  \
        gload_lds16(g_,      rg_ + sc * 4096 + sr * 16);                            \
        gload_lds16(g_ + 16, rg_ + (sc + 2) * 4096 + sr * 16);                      \
    } while (0)

#define RDA(buf, ks, mf) (*(const bf16x8*)(lds + (buf) * 65536 + (ks) * 16384 + lco + wr * 2048 + (mf) * 256))
#define RDB(buf, ks, nf) (*(const bf16x8*)(lds + (buf) * 65536 + 32768 + (ks) * 16384 + lco + wc * 1024 + (nf) * 256))

    // ---- prologue: tile0 fully + tile1 k0 halves (6 half-tiles, 12 loads) ----
    STAGE(xb,   brow, 0, 0, 0);
    STAGE(wcat, bcol, 0, 0, 32768);
    STAGE(xb,   brow, 0, 1, 0);
    STAGE(wcat, bcol, 0, 1, 32768);
    STAGE(xb,   brow, 1, 0, 0);
    STAGE(wcat, bcol, 1, 0, 32768);
    asm volatile("s_waitcnt vmcnt(4)" ::: "memory");   // tile0 landed; tile1-k0 in flight
    __builtin_amdgcn_s_barrier();

    for (int t = 0; t < 16; ++t) {
        const int buf = t & 1;
        bf16x8 a[4], a2[4], b[4];

        // ---- phase 0: k0, m-frags 0-3 ----
        #pragma unroll
        for (int mf = 0; mf < 4; ++mf) a[mf] = RDA(buf, 0, mf);
        #pragma unroll
        for (int nf = 0; nf < 4; ++nf) b[nf] = RDB(buf, 0, nf);
        STAGE(xb, brow, t + 1, 1, 0);               // A-k1(t+1) -> other buf
        __builtin_amdgcn_s_barrier();
        __builtin_amdgcn_s_setprio(1);
        #pragma unroll
        for (int mf = 0; mf < 4; ++mf)
            #pragma unroll
            for (int nf = 0; nf < 4; ++nf)
                acc[mf][nf] = __builtin_amdgcn_mfma_f32_16x16x32_bf16(a[mf], b[nf], acc[mf][nf], 0, 0, 0);
        __builtin_amdgcn_s_setprio(0);
        __builtin_amdgcn_s_barrier();

        // ---- phase 1: k0, m-frags 4-7 (reuse b) ----
        #pragma unroll
        for (int mf = 0; mf < 4; ++mf) a2[mf] = RDA(buf, 0, mf + 4);
        STAGE(wcat, bcol, t + 1, 1, 32768);         // B-k1(t+1) -> other buf
        __builtin_amdgcn_s_barrier();
        __builtin_amdgcn_s_setprio(1);
        #pragma unroll
        for (int mf = 0; mf < 4; ++mf)
            #pragma unroll
            for (int nf = 0; nf < 4; ++nf)
                acc[mf + 4][nf] = __builtin_amdgcn_mfma_f32_16x16x32_bf16(a2[mf], b[nf], acc[mf + 4][nf], 0, 0, 0);
        __builtin_amdgcn_s_setprio(0);
        __builtin_amdgcn_s_barrier();

        // ---- phase 2: k1, m-frags 0-3 ----
        #pragma unroll
        for (int mf = 0; mf < 4; ++mf) a[mf] = RDA(buf, 1, mf);
        #pragma unroll
        for (int nf = 0; nf < 4; ++nf) b[nf] = RDB(buf, 1, nf);
        STAGE(xb, brow, t + 2, 0, 0);               // A-k0(t+2) -> this buf (reads done ph1)
        __builtin_amdgcn_s_barrier();
        __builtin_amdgcn_s_setprio(1);
        #pragma unroll
        for (int mf = 0; mf < 4; ++mf)
            #pragma unroll
            for (int nf = 0; nf < 4; ++nf)
                acc[mf][nf] = __builtin_amdgcn_mfma_f32_16x16x32_bf16(a[mf], b[nf], acc[mf][nf], 0, 0, 0);
        __builtin_amdgcn_s_setprio(0);
        __builtin_amdgcn_s_barrier();

        // ---- phase 3: k1, m-frags 4-7 ----
        #pragma unroll
        for (int mf = 0; mf < 4; ++mf) a2[mf] = RDA(buf, 1, mf + 4);
        STAGE(wcat, bcol, t + 2, 0, 32768);         // B-k0(t+2) -> this buf (reads done ph0)
        __builtin_amdgcn_s_barrier();
        __builtin_amdgcn_s_setprio(1);
        #pragma unroll
        for (int mf = 0; mf < 4; ++mf)
            #pragma unroll
            for (int nf = 0; nf < 4; ++nf)
                acc[mf + 4][nf] = __builtin_amdgcn_mfma_f32_16x16x32_bf16(a2[mf], b[nf], acc[mf + 4][nf], 0, 0, 0);
        __builtin_amdgcn_s_setprio(0);
        // counted vmcnt: keep newest 4 loads (2 half-tiles) in flight across the barrier
        asm volatile("s_waitcnt vmcnt(4)" ::: "memory");
        __builtin_amdgcn_s_barrier();
    }

    // ---- C-write epilogue ----
    const bool is_z = (bcol < 1024);
    const int crow0 = brow + wr * 128 + (l >> 4) * 4;
    const int ccol0 = bcol + wc * 64 + (l & 15);
    if (unified) {
        #pragma unroll
        for (int nf = 0; nf < 4; ++nf) {
            int col = ccol0 + nf * 16;               // 0..2047
            float bb = is_z ? bias[col] : 0.f;
            #pragma unroll
            for (int mf = 0; mf < 8; ++mf) {
                int row = crow0 + mf * 16;
                f32x4 v = acc[mf][nf];
                #pragma unroll
                for (int j = 0; j < 4; ++j)
                    obuf[(size_t)(row + j) * 2048 + col] = f2bf(v[j] + bb);
            }
        }
    } else {
        #pragma unroll
        for (int nf = 0; nf < 4; ++nf) {
            int col = ccol0 + nf * 16;
            if (is_z) {
                float bb = bias[col];
                #pragma unroll
                for (int mf = 0; mf < 8; ++mf) {
                    int row = crow0 + mf * 16;
                    f32x4 v = acc[mf][nf];
                    #pragma unroll
                    for (int j = 0; j < 4; ++j)
                        zout[(size_t)(row + j) * 1024 + col] = v[j] + bb;
                }
            } else {
                int mc = col - 1024;
                #pragma unroll
                for (int mf = 0; mf < 8; ++mf) {
                    int row = crow0 + mf * 16;
                    f32x4 v = acc[mf][nf];
                    #pragma unroll
                    for (int j = 0; j < 4; ++j)
                        mbuf[(size_t)(row + j) * 1024 + mc] = f2bf(v[j]);
                }
            }
        }
    }
#undef STAGE
#undef RDA
#undef RDB
}

// ---------- kernel 5a: unified epilogue (z,m both bf16 in obuf) ----------
__global__ __launch_bounds__(256) void epilogue_u(const unsigned short* __restrict__ obuf,
                                                  float* __restrict__ out,
                                                  const int* __restrict__ lidx) {
    int row = blockIdx.x;            // 32768
    int tx = threadIdx.x;            // 256
    size_t zb = (size_t)row * 2048 + tx * 4;

    ushort4 zv = *(const ushort4*)&obuf[zb];
    ushort4 mv = *(const ushort4*)&obuf[zb + 1024];
    float z0 = bf2f(zv.x), z1 = bf2f(zv.y), z2 = bf2f(zv.z), z3 = bf2f(zv.w);
    float m0 = bf2f(mv.x), m1 = bf2f(mv.y), m2 = bf2f(mv.z), m3 = bf2f(mv.w);

    float sz = z0 * z0 + z1 * z1 + z2 * z2 + z3 * z3;
    float sm = m0 * m0 + m1 * m1 + m2 * m2 + m3 * m3;

    #pragma unroll
    for (int off = 32; off > 0; off >>= 1) {
        sz += __shfl_xor(sz, off);
        sm += __shfl_xor(sm, off);
    }
    __shared__ float red[8];
    int wv = tx >> 6;
    if ((tx & 63) == 0) { red[wv * 2] = sz; red[wv * 2 + 1] = sm; }
    __syncthreads();
    sz = red[0] + red[2] + red[4] + red[6];
    sm = red[1] + red[3] + red[5] + red[7];

    float gamma = fminf(0.5f * sqrtf(sz) / (sqrtf(sm) + 1e-6f), 1.0f);
    if (lidx[0] < 0) gamma = 0.f;

    float4 o;
    o.x = z0 + gamma * m0; o.y = z1 + gamma * m1;
    o.z = z2 + gamma * m2; o.w = z3 + gamma * m3;
    *(float4*)&out[(size_t)row * 1024 + tx * 4] = o;
}

// ---------- kernel 5b: fallback epilogue (z fp32 in d_out, m bf16) ----------
__global__ __launch_bounds__(256) void epilogue(float* __restrict__ out,
                                                const unsigned short* __restrict__ mbuf,
                                                const int* __restrict__ lidx) {
    int row = blockIdx.x;
    int tx = threadIdx.x;
    size_t base = (size_t)row * 1024 + tx * 4;

    float4 z = *(const float4*)&out[base];
    ushort4 mv = *(const ushort4*)&mbuf[base];
    float m0 = bf2f(mv.x), m1 = bf2f(mv.y), m2 = bf2f(mv.z), m3 = bf2f(mv.w);

    float sz = z.x * z.x + z.y * z.y + z.z * z.z + z.w * z.w;
    float sm = m0 * m0 + m1 * m1 + m2 * m2 + m3 * m3;

    #pragma unroll
    for (int off = 32; off > 0; off >>= 1) {
        sz += __shfl_xor(sz, off);
        sm += __shfl_xor(sm, off);
    }
    __shared__ float red[8];
    int wv = tx >> 6;
    if ((tx & 63) == 0) { red[wv * 2] = sz; red[wv * 2 + 1] = sm; }
    __syncthreads();
    sz = red[0] + red[2] + red[4] + red[6];
    sm = red[1] + red[3] + red[5] + red[7];

    float gamma = fminf(0.5f * sqrtf(sz) / (sqrtf(sm) + 1e-6f), 1.0f);
    if (lidx[0] < 0) gamma = 0.f;

    float4 o;
    o.x = z.x + gamma * m0; o.y = z.y + gamma * m1;
    o.z = z.z + gamma * m2; o.w = z.w + gamma * m3;
    *(float4*)&out[base] = o;
}

// ---------- launcher ----------
extern "C" void kernel_launch(void* const* d_in, const int* in_sizes, int n_in,
                              void* d_out, int out_size, void* d_ws, size_t ws_size,
                              hipStream_t stream) {
    const float* x  = (const float*)d_in[0];
    const float* W  = (const float*)d_in[1];
    const float* b  = (const float*)d_in[2];
    const float* A  = (const float*)d_in[3];
    const float* Bm = (const float*)d_in[4];
    const float* sc = (const float*)d_in[5];
    const int* lidx = (const int*)d_in[6];
    float* out = (float*)d_out;

    // ws layout: xb 64MB | wcat 4MB | obuf 128MB (unified)  or  mbuf 64MB (fallback)
    unsigned short* xb   = (unsigned short*)d_ws;
    unsigned short* wcat = (unsigned short*)((char*)d_ws + 67108864);
    unsigned short* buf2 = (unsigned short*)((char*)d_ws + 71303168);
    const int unified = (ws_size >= (size_t)71303168 + 134217728) ? 1 : 0;

    hipFuncSetAttribute((const void*)gemm_zm8,
                        hipFuncAttributeMaxDynamicSharedMemorySize, 131072);

    cast_x<<<2048, 256, 0, stream>>>(x, xb, 33554432 / 4);
    cast_w<<<1024, 256, 0, stream>>>(W, wcat);
    build_m<<<1024, 256, 0, stream>>>(A, Bm, sc, wcat);
    gemm_zm8<<<1024, 512, 131072, stream>>>(xb, wcat, b, out, buf2, buf2, unified);
    if (unified)
        epilogue_u<<<32768, 256, 0, stream>>>(buf2, out, lidx);
    else
        epilogue<<<32768, 256, 0, stream>>>(out, buf2, lidx);
}